// Round 10
// baseline (220.193 us; speedup 1.0000x reference)
//
#include <hip/hip_runtime.h>

typedef unsigned int uint;
typedef unsigned short ushort;

#define IN_C 128
#define HID  32

// ---- f16 helpers (fp32 accumulate everywhere; RNE on store) ---------------
__device__ __forceinline__ uint f2h2(float a, float b) {
    _Float16 ha = (_Float16)a, hb = (_Float16)b;
    unsigned short ua = __builtin_bit_cast(unsigned short, ha);
    unsigned short ub = __builtin_bit_cast(unsigned short, hb);
    return (uint)ua | ((uint)ub << 16);
}
// acc += f16_lo(pk) * v  -- single full-rate VOP3P v_fma_mix_f32, no unpack
__device__ __forceinline__ void fma_lo(float& acc, uint pk, float v) {
    asm("v_fma_mix_f32 %0, %1, %2, %0 op_sel:[0,0,0] op_sel_hi:[1,0,0]"
        : "+v"(acc) : "v"(pk), "v"(v));
}
// acc += f16_hi(pk) * v
__device__ __forceinline__ void fma_hi(float& acc, uint pk, float v) {
    asm("v_fma_mix_f32 %0, %1, %2, %0 op_sel:[1,0,0] op_sel_hi:[1,0,0]"
        : "+v"(acc) : "v"(pk), "v"(v));
}

// async global->LDS, 16 B per lane: lane i's 16B source -> ldsBase + i*16
typedef const __attribute__((address_space(1))) void* gas1_t;
typedef __attribute__((address_space(3))) void*       las3_t;
__device__ __forceinline__ void glds16(const void* g, void* l) {
    __builtin_amdgcn_global_load_lds((gas1_t)g, (las3_t)l, 16, 0, 0);
}
// R10: NT (non-temporal, CPol bit1) staging for the 33MB edge stream.
// Theory: the streamed col/val arrays thrash each XCD's 4MB private L2,
// evicting the 1.3-2.6MB feature table -> every gather becomes an
// L3-latency miss (explains level1==level2==41us, per-EDGE fixed cost).
// NT keeps the stream out of L2; gathers then hit local L2.
__device__ __forceinline__ void glds16nt(const void* g, void* l) {
    __builtin_amdgcn_global_load_lds((gas1_t)g, (las3_t)l, 16, 0, 2);
}

// manual-issue gather: 16B global load, 32-bit voffset + SGPR base.
// asm volatile => compiler neither tracks it (no auto-waitcnt insertion) nor
// reorders it relative to our manual s_waitcnt fences. We own the schedule.
__device__ __forceinline__ void gat_issue(uint4& d, const ushort* base, uint voff) {
    asm volatile("global_load_dwordx4 %0, %1, %2"
                 : "=v"(d) : "v"(voff), "s"(base));
}

// ---------------------------------------------------------------------------
// K1: fused prep (R5 version, unchanged).
// ---------------------------------------------------------------------------
__global__ void prep_kernel(const float* __restrict__ x,
                            const float* __restrict__ w,
                            ushort* __restrict__ r0,
                            const int* __restrict__ a1r, int E1, int* __restrict__ ip1,
                            const int* __restrict__ a2r, int E2, int* __restrict__ ip2,
                            const int* __restrict__ a2c, const float* __restrict__ a2v,
                            float* __restrict__ dummy,
                            int n, int nbE, int nbI, int nbT) {
    __shared__ float wl[IN_C * HID];
    const int tid = threadIdx.x;
    if (blockIdx.x < nbE) {
        for (int i = tid; i < IN_C * HID; i += blockDim.x) wl[i] = w[i];
        __syncthreads();
        const int row = blockIdx.x * 16 + tid / 16;
        const int h0  = (tid % 16) * 2;
        if (row >= n) return;
        const float4* xr = (const float4*)(x + (size_t)row * IN_C);
        float a0 = 0.f, a1 = 0.f;
#pragma unroll
        for (int k4 = 0; k4 < IN_C / 4; ++k4) {
            float4 xv = xr[k4];
            a0 += xv.x * wl[(4*k4+0)*HID + h0];  a1 += xv.x * wl[(4*k4+0)*HID + h0+1];
            a0 += xv.y * wl[(4*k4+1)*HID + h0];  a1 += xv.y * wl[(4*k4+1)*HID + h0+1];
            a0 += xv.z * wl[(4*k4+2)*HID + h0];  a1 += xv.z * wl[(4*k4+2)*HID + h0+1];
            a0 += xv.w * wl[(4*k4+3)*HID + h0];  a1 += xv.w * wl[(4*k4+3)*HID + h0+1];
        }
        uint p = f2h2(fmaxf(a0, 0.f), fmaxf(a1, 0.f));
        ((uint*)r0)[(size_t)row * 16 + (tid % 16)] = p;
    } else if (blockIdx.x < nbE + nbI) {
        const int i = (blockIdx.x - nbE) * 256 + tid;
        if (i > n) return;
        int lo = 0, hi = E1;
        while (lo < hi) { int m = (lo + hi) >> 1; if (a1r[m] < i) lo = m + 1; else hi = m; }
        ip1[i] = lo;
        lo = 0; hi = E2;
        while (lo < hi) { int m = (lo + hi) >> 1; if (a2r[m] < i) lo = m + 1; else hi = m; }
        ip2[i] = lo;
    } else {
        // warm-touch A2 edge arrays (coalesced stream; result dummy-used)
        const int t = (blockIdx.x - nbE - nbI) * 256 + tid;
        const int stride = nbT * 256;
        const int total4 = E2 / 4;
        const float4* c4 = (const float4*)a2c;
        const float4* v4 = (const float4*)a2v;
        float s = 0.f;
        for (int i = t; i < total4; i += stride) {
            float4 u = c4[i], v = v4[i];
            s += u.x + u.y + u.z + u.w + v.x + v.y + v.z + v.w;
        }
        if (s == 123.456f) dummy[0] = s;   // never true in practice; defeats DCE
    }
}

// ---------------------------------------------------------------------------
// K2: fused-level SpMM + ReLU, f16 features / fp32 accumulate (v_fma_mix).
// R10 = R9 (LDS-staged col+val, manual counted-vmcnt consume pipeline,
// verified best) with NT cache policy on the edge-stream staging loads.
// Blocks [0,nbH) = A2 (out col off C); rest = A1 (off 0).
// ---------------------------------------------------------------------------
template <int C, int ROWSL>
__global__ __launch_bounds__(256) void spmm_level(
        const int* __restrict__ ip1, const int* __restrict__ col1,
        const float* __restrict__ val1, int E1,
        const int* __restrict__ ip2, const int* __restrict__ col2,
        const float* __restrict__ val2, int E2,
        const ushort* __restrict__ xin, ushort* __restrict__ out,
        int n, int nbH) {
    constexpr int L = C / 8;                 // feature lanes per row (4 or 8)
    __shared__ __align__(16) int   scol[4][256];
    __shared__ __align__(16) float sval[4][256];

    const int lane = threadIdx.x & 63;
    const int wave = threadIdx.x >> 6;
    (void)E1;

    int bid = blockIdx.x;
    if (bid < nbH) {
        // ---------------- heavy path: A2, one row per wave -----------------
        constexpr int W = 64 / L;            // edge ways (16 for C=32, 8 for C=64)
        const int fl  = lane % L;
        const int way = lane / L;
        const uint flo = (uint)fl * 16u;

        auto gat = [&](uint c) -> uint4 {
            return *(const uint4*)((const char*)xin + (c * (uint)(2 * C) + flo));
        };
        float acc[8];
#pragma unroll
        for (int j = 0; j < 8; ++j) acc[j] = 0.f;
        auto fmadd = [&](const uint4& u, float v) {
            fma_lo(acc[0], u.x, v); fma_hi(acc[1], u.x, v);
            fma_lo(acc[2], u.y, v); fma_hi(acc[3], u.y, v);
            fma_lo(acc[4], u.z, v); fma_hi(acc[5], u.z, v);
            fma_lo(acc[6], u.w, v); fma_hi(acc[7], u.w, v);
        };

        const int row = bid * 4 + wave;
        if (row >= n) return;
        const int s = ip2[row];
        const int e = ip2[row + 1];

        // unaligned head (<=3 edges), straight from global
        int sv = (s + 3) & ~3; if (sv > e) sv = e;
        for (int idx = s + way; idx < sv; idx += W)
            fmadd(gat((uint)col2[idx]), val2[idx]);

        // global-array tail guard: edges >= cut handled direct-global
        const int cut = E2 & ~3;
        int ee = e;
        if (ee > cut) {
            int st = (sv > cut) ? sv : cut;
            for (int idx = st + way; idx < ee; idx += W)
                fmadd(gat((uint)col2[idx]), val2[idx]);
            ee = st;
        }

        const int lastA = (E2 - 4) & ~3;     // last aligned 4-int chunk start
        int*   myc = &scol[wave][0];
        float* myv = &sval[wave][0];

        for (int base = sv; base < ee; base += 256) {
            const int cnt = (ee - base < 256) ? (ee - base) : 256;
            // async stage this chunk's col+val, NT (keep stream out of L2)
            int so = base + lane * 4; if (so > lastA) so = lastA;
            glds16nt(col2 + so, myc);
            glds16nt(val2 + so, myv);
            asm volatile("s_waitcnt vmcnt(0)" ::: "memory");
            __builtin_amdgcn_sched_barrier(0);

            // -------- manually pipelined consume (2 batch slots) ----------
            const int nb = cnt / (4 * W);    // cnt uniform per wave -> uniform
            uint4 a0, a1, a2, a3, b0, b1, b2, b3;
            float4 vvA, vvB;
            if (nb > 0) {
                {   // prologue: batch 0 -> slot A
                    const int o = way * 4;
                    const int4 cc = *(const int4*)(myc + o);
                    vvA = *(const float4*)(myv + o);
                    gat_issue(a0, xin, (uint)cc.x * (uint)(2*C) + flo);
                    gat_issue(a1, xin, (uint)cc.y * (uint)(2*C) + flo);
                    gat_issue(a2, xin, (uint)cc.z * (uint)(2*C) + flo);
                    gat_issue(a3, xin, (uint)cc.w * (uint)(2*C) + flo);
                }
                for (int b = 0; b < nb; b += 2) {
                    // issue batch b+1 -> slot B; wait batch b (A)
                    if (b + 1 < nb) {
                        const int o = ((b + 1) * W + way) * 4;
                        const int4 cc = *(const int4*)(myc + o);
                        vvB = *(const float4*)(myv + o);
                        gat_issue(b0, xin, (uint)cc.x * (uint)(2*C) + flo);
                        gat_issue(b1, xin, (uint)cc.y * (uint)(2*C) + flo);
                        gat_issue(b2, xin, (uint)cc.z * (uint)(2*C) + flo);
                        gat_issue(b3, xin, (uint)cc.w * (uint)(2*C) + flo);
                        asm volatile("s_waitcnt vmcnt(4)");
                    } else {
                        asm volatile("s_waitcnt vmcnt(0)");
                    }
                    __builtin_amdgcn_sched_barrier(0);
                    fmadd(a0, vvA.x); fmadd(a1, vvA.y);
                    fmadd(a2, vvA.z); fmadd(a3, vvA.w);
                    if (b + 1 < nb) {
                        // issue batch b+2 -> slot A; wait batch b+1 (B)
                        if (b + 2 < nb) {
                            const int o = ((b + 2) * W + way) * 4;
                            const int4 cc = *(const int4*)(myc + o);
                            vvA = *(const float4*)(myv + o);
                            gat_issue(a0, xin, (uint)cc.x * (uint)(2*C) + flo);
                            gat_issue(a1, xin, (uint)cc.y * (uint)(2*C) + flo);
                            gat_issue(a2, xin, (uint)cc.z * (uint)(2*C) + flo);
                            gat_issue(a3, xin, (uint)cc.w * (uint)(2*C) + flo);
                            asm volatile("s_waitcnt vmcnt(4)");
                        } else {
                            asm volatile("s_waitcnt vmcnt(0)");
                        }
                        __builtin_amdgcn_sched_barrier(0);
                        fmadd(b0, vvB.x); fmadd(b1, vvB.y);
                        fmadd(b2, vvB.z); fmadd(b3, vvB.w);
                    }
                }
            }
            // per-edge tail within the chunk (0 outstanding at entry)
            for (int k = nb * 4 * W + way; k < cnt; k += W)
                fmadd(gat((uint)myc[k]), myv[k]);
        }

        // cross-way reduction (ways share a full wave here)
#pragma unroll
        for (int m = L; m < 64; m <<= 1)
#pragma unroll
            for (int j = 0; j < 8; ++j) acc[j] += __shfl_xor(acc[j], m, 64);

        if (way == 0) {
            uint4 p;
            p.x = f2h2(fmaxf(acc[0], 0.f), fmaxf(acc[1], 0.f));
            p.y = f2h2(fmaxf(acc[2], 0.f), fmaxf(acc[3], 0.f));
            p.z = f2h2(fmaxf(acc[4], 0.f), fmaxf(acc[5], 0.f));
            p.w = f2h2(fmaxf(acc[6], 0.f), fmaxf(acc[7], 0.f));
            *(uint4*)(out + (size_t)row * (2 * C) + C + fl * 8) = p;
        }
    } else {
        // ---------------- light path: A1 (R2 structure) --------------------
        bid -= nbH;
        constexpr int SUBL = 64 / ROWSL;
        constexpr int WL   = SUBL / L;
        const int sub = lane / SUBL;
        const int li  = lane % SUBL;
        const int fl  = li % L;
        const int way = li / L;
        const uint flo = (uint)fl * 16u;

        auto gat = [&](uint c) -> uint4 {
            return *(const uint4*)((const char*)xin + (c * (uint)(2 * C) + flo));
        };
        float acc[8];
#pragma unroll
        for (int j = 0; j < 8; ++j) acc[j] = 0.f;
        auto fmadd = [&](const uint4& u, float v) {
            fma_lo(acc[0], u.x, v); fma_hi(acc[1], u.x, v);
            fma_lo(acc[2], u.y, v); fma_hi(acc[3], u.y, v);
            fma_lo(acc[4], u.z, v); fma_hi(acc[5], u.z, v);
            fma_lo(acc[6], u.w, v); fma_hi(acc[7], u.w, v);
        };

        const int row = (bid * 4 + wave) * ROWSL + sub;
        if (row >= n) return;
        const int s = ip1[row];
        const int e = ip1[row + 1];
        int idx0 = s + way;
        if (idx0 < e) {
            int c0 = col1[idx0]; float v0 = val1[idx0];
            int idx1 = idx0 + WL;
            int c1 = 0; float v1 = 0.f;
            if (idx1 < e) { c1 = col1[idx1]; v1 = val1[idx1]; }
            uint4 g0 = gat((uint)c0);
            while (true) {
                int idx2 = idx1 + WL;
                int c2 = 0; float v2 = 0.f;
                if (idx2 < e) { c2 = col1[idx2]; v2 = val1[idx2]; }
                uint4 g1 = gat((uint)c1);
                fmadd(g0, v0);
                if (idx1 >= e) break;
                g0 = g1; c1 = c2; v0 = v1; v1 = v2;
                idx1 = idx2;
            }
        }
#pragma unroll
        for (int m = L; m < SUBL; m <<= 1)
#pragma unroll
            for (int j = 0; j < 8; ++j) acc[j] += __shfl_xor(acc[j], m, 64);
        if (way == 0) {
            uint4 p;
            p.x = f2h2(fmaxf(acc[0], 0.f), fmaxf(acc[1], 0.f));
            p.y = f2h2(fmaxf(acc[2], 0.f), fmaxf(acc[3], 0.f));
            p.z = f2h2(fmaxf(acc[4], 0.f), fmaxf(acc[5], 0.f));
            p.w = f2h2(fmaxf(acc[6], 0.f), fmaxf(acc[7], 0.f));
            *(uint4*)(out + (size_t)row * (2 * C) + fl * 8) = p;
        }
    }
}

// ---------------------------------------------------------------------------
// K3: classify (R8 version: 8 thr/row, 2 outs/thread, float2 weights).
// ---------------------------------------------------------------------------
#define CDIM 224
#define OUT_C 16
__global__ __launch_bounds__(256) void classify_kernel(
        const ushort* __restrict__ r0,
        const ushort* __restrict__ r1,
        const ushort* __restrict__ r2,
        const float* __restrict__ w,
        float* __restrict__ out, int n) {
    __shared__ float wl[CDIM * OUT_C];
    const int tid = threadIdx.x;
    for (int i = tid; i < CDIM * OUT_C; i += blockDim.x) wl[i] = w[i];
    __syncthreads();
    const int row = blockIdx.x * 32 + tid / 8;
    const int o   = (tid % 8) * 2;           // this thread's output pair
    if (row >= n) return;
    float acc0 = 0.f, acc1 = 0.f;

    auto wp = [&](int j) -> float2 {
        return *(const float2*)&wl[j * OUT_C + o];
    };
    auto step = [&](uint pk, int j) {
        float2 wa = wp(j);
        float2 wb = wp(j + 1);
        fma_lo(acc0, pk, wa.x); fma_lo(acc1, pk, wa.y);
        fma_hi(acc0, pk, wb.x); fma_hi(acc1, pk, wb.y);
    };

    const uint4* a = (const uint4*)(r0 + (size_t)row * 32);
#pragma unroll
    for (int q = 0; q < 4; ++q) {
        uint4 u = a[q]; int j = q * 8;
        step(u.x, j+0); step(u.y, j+2); step(u.z, j+4); step(u.w, j+6);
    }
    const uint4* b = (const uint4*)(r1 + (size_t)row * 64);
#pragma unroll
    for (int q = 0; q < 8; ++q) {
        uint4 u = b[q]; int j = 32 + q * 8;
        step(u.x, j+0); step(u.y, j+2); step(u.z, j+4); step(u.w, j+6);
    }
    const uint4* c = (const uint4*)(r2 + (size_t)row * 128);
#pragma unroll
    for (int q = 0; q < 16; ++q) {
        uint4 u = c[q]; int j = 96 + q * 8;
        step(u.x, j+0); step(u.y, j+2); step(u.z, j+4); step(u.w, j+6);
    }
    *(float2*)(out + (size_t)row * OUT_C + o) = make_float2(acc0, acc1);
}

// ---------------------------------------------------------------------------
extern "C" void kernel_launch(void* const* d_in, const int* in_sizes, int n_in,
                              void* d_out, int out_size, void* d_ws, size_t ws_size,
                              hipStream_t stream) {
    const float* x   = (const float*)d_in[0];
    const float* we  = (const float*)d_in[1];
    const float* wc  = (const float*)d_in[2];
    const int*   a1r = (const int*)  d_in[3];
    const int*   a1c = (const int*)  d_in[4];
    const float* a1v = (const float*)d_in[5];
    const int*   a2r = (const int*)  d_in[6];
    const int*   a2c = (const int*)  d_in[7];
    const float* a2v = (const float*)d_in[8];
    float* out = (float*)d_out;

    const int E1 = in_sizes[3];
    const int E2 = in_sizes[6];
    const int n  = in_sizes[0] / IN_C;   // 20000

    // Workspace (f16 features): r0[n*32] r1[n*64] r2[n*128], ip1/ip2, dummy
    ushort* r0 = (ushort*)d_ws;
    ushort* r1 = r0 + (size_t)n * 32;
    ushort* r2 = r1 + (size_t)n * 64;
    int*   ip1 = (int*)(r2 + (size_t)n * 128);
    int*   ip2 = ip1 + (n + 1);
    float* dummy = (float*)(ip2 + (n + 2));

    // 1) fused embed + indptr + A2 edge-list warm-touch
    {
        const int nbE = (n + 15) / 16;
        const int nbI = (n + 1 + 255) / 256;
        const int nbT = 512;
        prep_kernel<<<nbE + nbI + nbT, 256, 0, stream>>>(
            x, we, r0, a1r, E1, ip1, a2r, E2, ip2, a2c, a2v, dummy,
            n, nbE, nbI, nbT);
    }

    // 2) level 1: r1 = relu([A1 r0 | A2 r0]); C=32
    //    heavy: 1 row/wave (4 rows/block); light: ROWSL=2 (8 rows/block)
    {
        const int nbH = (n + 3) / 4;
        const int nbL = (n + 7) / 8;
        spmm_level<32, 2><<<nbH + nbL, 256, 0, stream>>>(
            ip1, a1c, a1v, E1, ip2, a2c, a2v, E2, r0, r1, n, nbH);
    }
    // 3) level 2: r2 = relu([A1 r1 | A2 r1]); C=64
    //    heavy: 1 row/wave (4 rows/block); light: ROWSL=1 (4 rows/block)
    {
        const int nbH = (n + 3) / 4;
        const int nbL = (n + 3) / 4;
        spmm_level<64, 1><<<nbH + nbL, 256, 0, stream>>>(
            ip1, a1c, a1v, E1, ip2, a2c, a2v, E2, r1, r2, n, nbH);
    }

    // 4) fused concat + classify (32 rows/block, 2 outs/thread, b64 weights)
    classify_kernel<<<(n + 31) / 32, 256, 0, stream>>>(r0, r1, r2, wc, out, n);
}

// Round 11
// 217.988 us; speedup vs baseline: 1.0101x; 1.0101x over previous
//
#include <hip/hip_runtime.h>

typedef unsigned int uint;
typedef unsigned short ushort;

#define IN_C 128
#define HID  32

// ---- f16 helpers (fp32 accumulate everywhere; RNE on store) ---------------
__device__ __forceinline__ uint f2h2(float a, float b) {
    _Float16 ha = (_Float16)a, hb = (_Float16)b;
    unsigned short ua = __builtin_bit_cast(unsigned short, ha);
    unsigned short ub = __builtin_bit_cast(unsigned short, hb);
    return (uint)ua | ((uint)ub << 16);
}
// acc += f16_lo(pk) * v  -- single full-rate VOP3P v_fma_mix_f32, no unpack
__device__ __forceinline__ void fma_lo(float& acc, uint pk, float v) {
    asm("v_fma_mix_f32 %0, %1, %2, %0 op_sel:[0,0,0] op_sel_hi:[1,0,0]"
        : "+v"(acc) : "v"(pk), "v"(v));
}
// acc += f16_hi(pk) * v
__device__ __forceinline__ void fma_hi(float& acc, uint pk, float v) {
    asm("v_fma_mix_f32 %0, %1, %2, %0 op_sel:[1,0,0] op_sel_hi:[1,0,0]"
        : "+v"(acc) : "v"(pk), "v"(v));
}

// manual-issue 16B global load, 32-bit voffset + SGPR base (we own the
// schedule: compiler neither tracks these for waitcnt nor reorders them).
__device__ __forceinline__ void gat_issue(uint4& d, const ushort* base, uint voff) {
    asm volatile("global_load_dwordx4 %0, %1, %2"
                 : "=v"(d) : "v"(voff), "s"(base));
}
// R11: NT variant for the 33MB streaming edge arrays. Theory: the edge
// stream allocates in each XCD's 4MB private L2 (~4MB/XCD/dispatch) and
// continuously evicts the 1.3-2.6MB feature table -> gathers run at
// L3 latency (explains level1==level2==41us: per-EDGE fixed cost).
// `nt` keeps the stream out of L2. (R10's glds16 aux=2 was an unverified
// CPol encoding and regressed; `nt` is the gfx950-verified flag spelling.)
__device__ __forceinline__ void gat_issue_nt_i(int4& d, const int* base, uint voff) {
    asm volatile("global_load_dwordx4 %0, %1, %2 nt"
                 : "=v"(d) : "v"(voff), "s"(base));
}
__device__ __forceinline__ void gat_issue_nt_f(float4& d, const float* base, uint voff) {
    asm volatile("global_load_dwordx4 %0, %1, %2 nt"
                 : "=v"(d) : "v"(voff), "s"(base));
}

// ---------------------------------------------------------------------------
// K1: fused prep (R5 version, unchanged).
// ---------------------------------------------------------------------------
__global__ void prep_kernel(const float* __restrict__ x,
                            const float* __restrict__ w,
                            ushort* __restrict__ r0,
                            const int* __restrict__ a1r, int E1, int* __restrict__ ip1,
                            const int* __restrict__ a2r, int E2, int* __restrict__ ip2,
                            const int* __restrict__ a2c, const float* __restrict__ a2v,
                            float* __restrict__ dummy,
                            int n, int nbE, int nbI, int nbT) {
    __shared__ float wl[IN_C * HID];
    const int tid = threadIdx.x;
    if (blockIdx.x < nbE) {
        for (int i = tid; i < IN_C * HID; i += blockDim.x) wl[i] = w[i];
        __syncthreads();
        const int row = blockIdx.x * 16 + tid / 16;
        const int h0  = (tid % 16) * 2;
        if (row >= n) return;
        const float4* xr = (const float4*)(x + (size_t)row * IN_C);
        float a0 = 0.f, a1 = 0.f;
#pragma unroll
        for (int k4 = 0; k4 < IN_C / 4; ++k4) {
            float4 xv = xr[k4];
            a0 += xv.x * wl[(4*k4+0)*HID + h0];  a1 += xv.x * wl[(4*k4+0)*HID + h0+1];
            a0 += xv.y * wl[(4*k4+1)*HID + h0];  a1 += xv.y * wl[(4*k4+1)*HID + h0+1];
            a0 += xv.z * wl[(4*k4+2)*HID + h0];  a1 += xv.z * wl[(4*k4+2)*HID + h0+1];
            a0 += xv.w * wl[(4*k4+3)*HID + h0];  a1 += xv.w * wl[(4*k4+3)*HID + h0+1];
        }
        uint p = f2h2(fmaxf(a0, 0.f), fmaxf(a1, 0.f));
        ((uint*)r0)[(size_t)row * 16 + (tid % 16)] = p;
    } else if (blockIdx.x < nbE + nbI) {
        const int i = (blockIdx.x - nbE) * 256 + tid;
        if (i > n) return;
        int lo = 0, hi = E1;
        while (lo < hi) { int m = (lo + hi) >> 1; if (a1r[m] < i) lo = m + 1; else hi = m; }
        ip1[i] = lo;
        lo = 0; hi = E2;
        while (lo < hi) { int m = (lo + hi) >> 1; if (a2r[m] < i) lo = m + 1; else hi = m; }
        ip2[i] = lo;
    } else {
        // warm-touch A2 edge arrays into L3 (coalesced stream; dummy-used)
        const int t = (blockIdx.x - nbE - nbI) * 256 + tid;
        const int stride = nbT * 256;
        const int total4 = E2 / 4;
        const float4* c4 = (const float4*)a2c;
        const float4* v4 = (const float4*)a2v;
        float s = 0.f;
        for (int i = t; i < total4; i += stride) {
            float4 u = c4[i], v = v4[i];
            s += u.x + u.y + u.z + u.w + v.x + v.y + v.z + v.w;
        }
        if (s == 123.456f) dummy[0] = s;   // never true in practice; defeats DCE
    }
}

// ---------------------------------------------------------------------------
// K2: fused-level SpMM + ReLU, f16 features / fp32 accumulate (v_fma_mix).
// R11 = R9 (LDS-staged edges, manual counted-vmcnt consume pipeline; best)
// with the chunk staging switched from global_load_lds (aux=0, allocates
// L2) to asm NT loads -> registers -> ds_write_b128. Stream stays out of
// L2; the feature table stops being evicted; gathers should hit local L2.
// Stage stall (vmcnt(0) per chunk) unchanged -> isolates cache policy only.
// Blocks [0,nbH) = A2 (out col off C); rest = A1 (off 0).
// ---------------------------------------------------------------------------
template <int C, int ROWSL>
__global__ __launch_bounds__(256) void spmm_level(
        const int* __restrict__ ip1, const int* __restrict__ col1,
        const float* __restrict__ val1, int E1,
        const int* __restrict__ ip2, const int* __restrict__ col2,
        const float* __restrict__ val2, int E2,
        const ushort* __restrict__ xin, ushort* __restrict__ out,
        int n, int nbH) {
    constexpr int L = C / 8;                 // feature lanes per row (4 or 8)
    __shared__ __align__(16) int   scol[4][256];
    __shared__ __align__(16) float sval[4][256];

    const int lane = threadIdx.x & 63;
    const int wave = threadIdx.x >> 6;
    (void)E1;

    int bid = blockIdx.x;
    if (bid < nbH) {
        // ---------------- heavy path: A2, one row per wave -----------------
        constexpr int W = 64 / L;            // edge ways (16 for C=32, 8 for C=64)
        const int fl  = lane % L;
        const int way = lane / L;
        const uint flo = (uint)fl * 16u;

        auto gat = [&](uint c) -> uint4 {
            return *(const uint4*)((const char*)xin + (c * (uint)(2 * C) + flo));
        };
        float acc[8];
#pragma unroll
        for (int j = 0; j < 8; ++j) acc[j] = 0.f;
        auto fmadd = [&](const uint4& u, float v) {
            fma_lo(acc[0], u.x, v); fma_hi(acc[1], u.x, v);
            fma_lo(acc[2], u.y, v); fma_hi(acc[3], u.y, v);
            fma_lo(acc[4], u.z, v); fma_hi(acc[5], u.z, v);
            fma_lo(acc[6], u.w, v); fma_hi(acc[7], u.w, v);
        };

        const int row = bid * 4 + wave;
        if (row >= n) return;
        const int s = ip2[row];
        const int e = ip2[row + 1];

        // unaligned head (<=3 edges), straight from global
        int sv = (s + 3) & ~3; if (sv > e) sv = e;
        for (int idx = s + way; idx < sv; idx += W)
            fmadd(gat((uint)col2[idx]), val2[idx]);

        // global-array tail guard: edges >= cut handled direct-global
        const int cut = E2 & ~3;
        int ee = e;
        if (ee > cut) {
            int st = (sv > cut) ? sv : cut;
            for (int idx = st + way; idx < ee; idx += W)
                fmadd(gat((uint)col2[idx]), val2[idx]);
            ee = st;
        }

        const int lastA = (E2 - 4) & ~3;     // last aligned 4-int chunk start
        int*   myc = &scol[wave][0];
        float* myv = &sval[wave][0];

        for (int base = sv; base < ee; base += 256) {
            const int cnt = (ee - base < 256) ? (ee - base) : 256;
            // stage this chunk's col+val: NT loads -> regs -> LDS
            int so = base + lane * 4; if (so > lastA) so = lastA;
            int4   stc; float4 stv;
            __builtin_amdgcn_sched_barrier(0);
            gat_issue_nt_i(stc, col2, (uint)so * 4u);
            gat_issue_nt_f(stv, val2, (uint)so * 4u);
            asm volatile("s_waitcnt vmcnt(0)" ::: "memory");
            __builtin_amdgcn_sched_barrier(0);
            *(int4*)  (myc + lane * 4) = stc;   // ds_write_b128
            *(float4*)(myv + lane * 4) = stv;   // (wave-local; compiler orders
                                                //  ds_write->ds_read via lgkmcnt)

            // -------- manually pipelined consume (2 batch slots) ----------
            const int nb = cnt / (4 * W);    // cnt uniform per wave -> uniform
            uint4 a0, a1, a2, a3, b0, b1, b2, b3;
            float4 vvA, vvB;
            if (nb > 0) {
                {   // prologue: batch 0 -> slot A
                    const int o = way * 4;
                    const int4 cc = *(const int4*)(myc + o);
                    vvA = *(const float4*)(myv + o);
                    gat_issue(a0, xin, (uint)cc.x * (uint)(2*C) + flo);
                    gat_issue(a1, xin, (uint)cc.y * (uint)(2*C) + flo);
                    gat_issue(a2, xin, (uint)cc.z * (uint)(2*C) + flo);
                    gat_issue(a3, xin, (uint)cc.w * (uint)(2*C) + flo);
                }
                for (int b = 0; b < nb; b += 2) {
                    // issue batch b+1 -> slot B; wait batch b (A)
                    if (b + 1 < nb) {
                        const int o = ((b + 1) * W + way) * 4;
                        const int4 cc = *(const int4*)(myc + o);
                        vvB = *(const float4*)(myv + o);
                        gat_issue(b0, xin, (uint)cc.x * (uint)(2*C) + flo);
                        gat_issue(b1, xin, (uint)cc.y * (uint)(2*C) + flo);
                        gat_issue(b2, xin, (uint)cc.z * (uint)(2*C) + flo);
                        gat_issue(b3, xin, (uint)cc.w * (uint)(2*C) + flo);
                        asm volatile("s_waitcnt vmcnt(4)");
                    } else {
                        asm volatile("s_waitcnt vmcnt(0)");
                    }
                    __builtin_amdgcn_sched_barrier(0);
                    fmadd(a0, vvA.x); fmadd(a1, vvA.y);
                    fmadd(a2, vvA.z); fmadd(a3, vvA.w);
                    if (b + 1 < nb) {
                        // issue batch b+2 -> slot A; wait batch b+1 (B)
                        if (b + 2 < nb) {
                            const int o = ((b + 2) * W + way) * 4;
                            const int4 cc = *(const int4*)(myc + o);
                            vvA = *(const float4*)(myv + o);
                            gat_issue(a0, xin, (uint)cc.x * (uint)(2*C) + flo);
                            gat_issue(a1, xin, (uint)cc.y * (uint)(2*C) + flo);
                            gat_issue(a2, xin, (uint)cc.z * (uint)(2*C) + flo);
                            gat_issue(a3, xin, (uint)cc.w * (uint)(2*C) + flo);
                            asm volatile("s_waitcnt vmcnt(4)");
                        } else {
                            asm volatile("s_waitcnt vmcnt(0)");
                        }
                        __builtin_amdgcn_sched_barrier(0);
                        fmadd(b0, vvB.x); fmadd(b1, vvB.y);
                        fmadd(b2, vvB.z); fmadd(b3, vvB.w);
                    }
                }
            }
            // per-edge tail within the chunk (0 outstanding at entry)
            for (int k = nb * 4 * W + way; k < cnt; k += W)
                fmadd(gat((uint)myc[k]), myv[k]);
        }

        // cross-way reduction (ways share a full wave here)
#pragma unroll
        for (int m = L; m < 64; m <<= 1)
#pragma unroll
            for (int j = 0; j < 8; ++j) acc[j] += __shfl_xor(acc[j], m, 64);

        if (way == 0) {
            uint4 p;
            p.x = f2h2(fmaxf(acc[0], 0.f), fmaxf(acc[1], 0.f));
            p.y = f2h2(fmaxf(acc[2], 0.f), fmaxf(acc[3], 0.f));
            p.z = f2h2(fmaxf(acc[4], 0.f), fmaxf(acc[5], 0.f));
            p.w = f2h2(fmaxf(acc[6], 0.f), fmaxf(acc[7], 0.f));
            *(uint4*)(out + (size_t)row * (2 * C) + C + fl * 8) = p;
        }
    } else {
        // ---------------- light path: A1 (R2 structure) --------------------
        bid -= nbH;
        constexpr int SUBL = 64 / ROWSL;
        constexpr int WL   = SUBL / L;
        const int sub = lane / SUBL;
        const int li  = lane % SUBL;
        const int fl  = li % L;
        const int way = li / L;
        const uint flo = (uint)fl * 16u;

        auto gat = [&](uint c) -> uint4 {
            return *(const uint4*)((const char*)xin + (c * (uint)(2 * C) + flo));
        };
        float acc[8];
#pragma unroll
        for (int j = 0; j < 8; ++j) acc[j] = 0.f;
        auto fmadd = [&](const uint4& u, float v) {
            fma_lo(acc[0], u.x, v); fma_hi(acc[1], u.x, v);
            fma_lo(acc[2], u.y, v); fma_hi(acc[3], u.y, v);
            fma_lo(acc[4], u.z, v); fma_hi(acc[5], u.z, v);
            fma_lo(acc[6], u.w, v); fma_hi(acc[7], u.w, v);
        };

        const int row = (bid * 4 + wave) * ROWSL + sub;
        if (row >= n) return;
        const int s = ip1[row];
        const int e = ip1[row + 1];
        int idx0 = s + way;
        if (idx0 < e) {
            int c0 = col1[idx0]; float v0 = val1[idx0];
            int idx1 = idx0 + WL;
            int c1 = 0; float v1 = 0.f;
            if (idx1 < e) { c1 = col1[idx1]; v1 = val1[idx1]; }
            uint4 g0 = gat((uint)c0);
            while (true) {
                int idx2 = idx1 + WL;
                int c2 = 0; float v2 = 0.f;
                if (idx2 < e) { c2 = col1[idx2]; v2 = val1[idx2]; }
                uint4 g1 = gat((uint)c1);
                fmadd(g0, v0);
                if (idx1 >= e) break;
                g0 = g1; c1 = c2; v0 = v1; v1 = v2;
                idx1 = idx2;
            }
        }
#pragma unroll
        for (int m = L; m < SUBL; m <<= 1)
#pragma unroll
            for (int j = 0; j < 8; ++j) acc[j] += __shfl_xor(acc[j], m, 64);
        if (way == 0) {
            uint4 p;
            p.x = f2h2(fmaxf(acc[0], 0.f), fmaxf(acc[1], 0.f));
            p.y = f2h2(fmaxf(acc[2], 0.f), fmaxf(acc[3], 0.f));
            p.z = f2h2(fmaxf(acc[4], 0.f), fmaxf(acc[5], 0.f));
            p.w = f2h2(fmaxf(acc[6], 0.f), fmaxf(acc[7], 0.f));
            *(uint4*)(out + (size_t)row * (2 * C) + fl * 8) = p;
        }
    }
}

// ---------------------------------------------------------------------------
// K3: classify (R8 version: 8 thr/row, 2 outs/thread, float2 weights).
// ---------------------------------------------------------------------------
#define CDIM 224
#define OUT_C 16
__global__ __launch_bounds__(256) void classify_kernel(
        const ushort* __restrict__ r0,
        const ushort* __restrict__ r1,
        const ushort* __restrict__ r2,
        const float* __restrict__ w,
        float* __restrict__ out, int n) {
    __shared__ float wl[CDIM * OUT_C];
    const int tid = threadIdx.x;
    for (int i = tid; i < CDIM * OUT_C; i += blockDim.x) wl[i] = w[i];
    __syncthreads();
    const int row = blockIdx.x * 32 + tid / 8;
    const int o   = (tid % 8) * 2;           // this thread's output pair
    if (row >= n) return;
    float acc0 = 0.f, acc1 = 0.f;

    auto wp = [&](int j) -> float2 {
        return *(const float2*)&wl[j * OUT_C + o];
    };
    auto step = [&](uint pk, int j) {
        float2 wa = wp(j);
        float2 wb = wp(j + 1);
        fma_lo(acc0, pk, wa.x); fma_lo(acc1, pk, wa.y);
        fma_hi(acc0, pk, wb.x); fma_hi(acc1, pk, wb.y);
    };

    const uint4* a = (const uint4*)(r0 + (size_t)row * 32);
#pragma unroll
    for (int q = 0; q < 4; ++q) {
        uint4 u = a[q]; int j = q * 8;
        step(u.x, j+0); step(u.y, j+2); step(u.z, j+4); step(u.w, j+6);
    }
    const uint4* b = (const uint4*)(r1 + (size_t)row * 64);
#pragma unroll
    for (int q = 0; q < 8; ++q) {
        uint4 u = b[q]; int j = 32 + q * 8;
        step(u.x, j+0); step(u.y, j+2); step(u.z, j+4); step(u.w, j+6);
    }
    const uint4* c = (const uint4*)(r2 + (size_t)row * 128);
#pragma unroll
    for (int q = 0; q < 16; ++q) {
        uint4 u = c[q]; int j = 96 + q * 8;
        step(u.x, j+0); step(u.y, j+2); step(u.z, j+4); step(u.w, j+6);
    }
    *(float2*)(out + (size_t)row * OUT_C + o) = make_float2(acc0, acc1);
}

// ---------------------------------------------------------------------------
extern "C" void kernel_launch(void* const* d_in, const int* in_sizes, int n_in,
                              void* d_out, int out_size, void* d_ws, size_t ws_size,
                              hipStream_t stream) {
    const float* x   = (const float*)d_in[0];
    const float* we  = (const float*)d_in[1];
    const float* wc  = (const float*)d_in[2];
    const int*   a1r = (const int*)  d_in[3];
    const int*   a1c = (const int*)  d_in[4];
    const float* a1v = (const float*)d_in[5];
    const int*   a2r = (const int*)  d_in[6];
    const int*   a2c = (const int*)  d_in[7];
    const float* a2v = (const float*)d_in[8];
    float* out = (float*)d_out;

    const int E1 = in_sizes[3];
    const int E2 = in_sizes[6];
    const int n  = in_sizes[0] / IN_C;   // 20000

    // Workspace (f16 features): r0[n*32] r1[n*64] r2[n*128], ip1/ip2, dummy
    ushort* r0 = (ushort*)d_ws;
    ushort* r1 = r0 + (size_t)n * 32;
    ushort* r2 = r1 + (size_t)n * 64;
    int*   ip1 = (int*)(r2 + (size_t)n * 128);
    int*   ip2 = ip1 + (n + 1);
    float* dummy = (float*)(ip2 + (n + 2));

    // 1) fused embed + indptr + A2 edge-list warm-touch
    {
        const int nbE = (n + 15) / 16;
        const int nbI = (n + 1 + 255) / 256;
        const int nbT = 512;
        prep_kernel<<<nbE + nbI + nbT, 256, 0, stream>>>(
            x, we, r0, a1r, E1, ip1, a2r, E2, ip2, a2c, a2v, dummy,
            n, nbE, nbI, nbT);
    }

    // 2) level 1: r1 = relu([A1 r0 | A2 r0]); C=32
    //    heavy: 1 row/wave (4 rows/block); light: ROWSL=2 (8 rows/block)
    {
        const int nbH = (n + 3) / 4;
        const int nbL = (n + 7) / 8;
        spmm_level<32, 2><<<nbH + nbL, 256, 0, stream>>>(
            ip1, a1c, a1v, E1, ip2, a2c, a2v, E2, r0, r1, n, nbH);
    }
    // 3) level 2: r2 = relu([A1 r1 | A2 r1]); C=64
    //    heavy: 1 row/wave (4 rows/block); light: ROWSL=1 (4 rows/block)
    {
        const int nbH = (n + 3) / 4;
        const int nbL = (n + 3) / 4;
        spmm_level<64, 1><<<nbH + nbL, 256, 0, stream>>>(
            ip1, a1c, a1v, E1, ip2, a2c, a2v, E2, r1, r2, n, nbH);
    }

    // 4) fused concat + classify (32 rows/block, 2 outs/thread, b64 weights)
    classify_kernel<<<(n + 31) / 32, 256, 0, stream>>>(r0, r1, r2, wc, out, n);
}

// Round 12
// 203.490 us; speedup vs baseline: 1.0821x; 1.0713x over previous
//
#include <hip/hip_runtime.h>

typedef unsigned int uint;
typedef unsigned short ushort;

#define IN_C 128
#define HID  32

// ---- f16 helpers (fp32 accumulate everywhere; RNE on store) ---------------
__device__ __forceinline__ uint f2h2(float a, float b) {
    _Float16 ha = (_Float16)a, hb = (_Float16)b;
    unsigned short ua = __builtin_bit_cast(unsigned short, ha);
    unsigned short ub = __builtin_bit_cast(unsigned short, hb);
    return (uint)ua | ((uint)ub << 16);
}
__device__ __forceinline__ ushort f2h1(float a) {
    _Float16 ha = (_Float16)a;
    return __builtin_bit_cast(unsigned short, ha);
}
__device__ __forceinline__ float h2f_hi(uint p) {
    ushort h = (ushort)(p >> 16);
    _Float16 f = __builtin_bit_cast(_Float16, h);
    return (float)f;
}
// acc += f16_lo(pk) * v(f32)  -- single full-rate VOP3P v_fma_mix_f32
__device__ __forceinline__ void fma_lo(float& acc, uint pk, float v) {
    asm("v_fma_mix_f32 %0, %1, %2, %0 op_sel:[0,0,0] op_sel_hi:[1,0,0]"
        : "+v"(acc) : "v"(pk), "v"(v));
}
__device__ __forceinline__ void fma_hi(float& acc, uint pk, float v) {
    asm("v_fma_mix_f32 %0, %1, %2, %0 op_sel:[1,0,0] op_sel_hi:[1,0,0]"
        : "+v"(acc) : "v"(pk), "v"(v));
}
// R12: f16-feature x f16-val (hi half of packed edge word) -> fp32 acc.
// op_sel picks halves; op_sel_hi declares both srcs f16. Zero unpack VALU.
__device__ __forceinline__ void fma_lo16(float& acc, uint featpk, uint edgepk) {
    asm("v_fma_mix_f32 %0, %1, %2, %0 op_sel:[0,1,0] op_sel_hi:[1,1,0]"
        : "+v"(acc) : "v"(featpk), "v"(edgepk));
}
__device__ __forceinline__ void fma_hi16(float& acc, uint featpk, uint edgepk) {
    asm("v_fma_mix_f32 %0, %1, %2, %0 op_sel:[1,1,0] op_sel_hi:[1,1,0]"
        : "+v"(acc) : "v"(featpk), "v"(edgepk));
}

// async global->LDS, 16 B per lane: lane i's 16B source -> ldsBase + i*16
typedef const __attribute__((address_space(1))) void* gas1_t;
typedef __attribute__((address_space(3))) void*       las3_t;
__device__ __forceinline__ void glds16(const void* g, void* l) {
    __builtin_amdgcn_global_load_lds((gas1_t)g, (las3_t)l, 16, 0, 0);
}

// ---------------------------------------------------------------------------
// K1: fused prep.
//   blocks [0,nbE)       : r0 = relu(x @ w_embed) -> f16
//   blocks [nbE,nbE+nbI) : both CSR indptrs by binary search
//   rest                 : repack A2 edges to 4B {u16 col | f16 val}
//                          (doubles as the warm-touch; halves the stream the
//                          spmm pushes through L2 -> stops feature eviction)
// ---------------------------------------------------------------------------
__global__ void prep_kernel(const float* __restrict__ x,
                            const float* __restrict__ w,
                            ushort* __restrict__ r0,
                            const int* __restrict__ a1r, int E1, int* __restrict__ ip1,
                            const int* __restrict__ a2r, int E2, int* __restrict__ ip2,
                            const int* __restrict__ a2c, const float* __restrict__ a2v,
                            uint* __restrict__ pk2,
                            int n, int nbE, int nbI, int nbT) {
    const int tid = threadIdx.x;
    if (blockIdx.x < nbE) {
        __shared__ float wl[IN_C * HID];
        for (int i = tid; i < IN_C * HID; i += blockDim.x) wl[i] = w[i];
        __syncthreads();
        const int row = blockIdx.x * 16 + tid / 16;
        const int h0  = (tid % 16) * 2;
        if (row >= n) return;
        const float4* xr = (const float4*)(x + (size_t)row * IN_C);
        float a0 = 0.f, a1 = 0.f;
#pragma unroll
        for (int k4 = 0; k4 < IN_C / 4; ++k4) {
            float4 xv = xr[k4];
            a0 += xv.x * wl[(4*k4+0)*HID + h0];  a1 += xv.x * wl[(4*k4+0)*HID + h0+1];
            a0 += xv.y * wl[(4*k4+1)*HID + h0];  a1 += xv.y * wl[(4*k4+1)*HID + h0+1];
            a0 += xv.z * wl[(4*k4+2)*HID + h0];  a1 += xv.z * wl[(4*k4+2)*HID + h0+1];
            a0 += xv.w * wl[(4*k4+3)*HID + h0];  a1 += xv.w * wl[(4*k4+3)*HID + h0+1];
        }
        uint p = f2h2(fmaxf(a0, 0.f), fmaxf(a1, 0.f));
        ((uint*)r0)[(size_t)row * 16 + (tid % 16)] = p;
    } else if (blockIdx.x < nbE + nbI) {
        const int i = (blockIdx.x - nbE) * 256 + tid;
        if (i > n) return;
        int lo = 0, hi = E1;
        while (lo < hi) { int m = (lo + hi) >> 1; if (a1r[m] < i) lo = m + 1; else hi = m; }
        ip1[i] = lo;
        lo = 0; hi = E2;
        while (lo < hi) { int m = (lo + hi) >> 1; if (a2r[m] < i) lo = m + 1; else hi = m; }
        ip2[i] = lo;
    } else {
        // repack A2 edges: {u16 col | f16 val} (n < 65536; val in (0,1])
        const int t = (blockIdx.x - nbE - nbI) * 256 + tid;
        const int stride = nbT * 256;
        const int total4 = E2 / 4;
        const int4*   c4 = (const int4*)a2c;
        const float4* v4 = (const float4*)a2v;
        uint4* p4 = (uint4*)pk2;
        for (int i = t; i < total4; i += stride) {
            int4   c = c4[i];
            float4 v = v4[i];
            uint4 p;
            p.x = ((uint)c.x & 0xffffu) | ((uint)f2h1(v.x) << 16);
            p.y = ((uint)c.y & 0xffffu) | ((uint)f2h1(v.y) << 16);
            p.z = ((uint)c.z & 0xffffu) | ((uint)f2h1(v.z) << 16);
            p.w = ((uint)c.w & 0xffffu) | ((uint)f2h1(v.w) << 16);
            p4[i] = p;
        }
        if (t == 0) {
            for (int i = total4 * 4; i < E2; ++i)
                pk2[i] = ((uint)a2c[i] & 0xffffu) | ((uint)f2h1(a2v[i]) << 16);
        }
    }
}

// ---------------------------------------------------------------------------
// K2: fused-level SpMM + ReLU, f16 features / fp32 accumulate (v_fma_mix).
// R12 = R8 skeleton (LDS-staged edges, vmcnt(0) once per 256-edge chunk --
// the verified-best structure after 7 alternatives regressed) with the heavy
// (A2) edge stream packed to 4B/edge:
//   - one glds16 stages a whole 256-edge chunk (was two);
//   - stream bytes through L2 halve (33->16.5MB): stream/XCD ~2MB + feature
//     table 1.3-2.6MB now FIT the 4MB private L2 -> gathers stop missing;
//   - f16 val multiplies via v_fma_mix op_sel (no unpack VALU).
// Light (A1) path = R2 depth-1 pipeline, unchanged (A1 is only ~2MB).
// Blocks [0,nbH) = A2 (out col off C); rest = A1 (off 0).
// ---------------------------------------------------------------------------
template <int C, int ROWSL>
__global__ __launch_bounds__(256) void spmm_level(
        const int* __restrict__ ip1, const int* __restrict__ col1,
        const float* __restrict__ val1,
        const int* __restrict__ ip2, const uint* __restrict__ pk2, int E2,
        const ushort* __restrict__ xin, ushort* __restrict__ out,
        int n, int nbH) {
    constexpr int L = C / 8;                 // feature lanes per row (4 or 8)
    __shared__ __align__(16) uint spk[4][256];

    const int lane = threadIdx.x & 63;
    const int wave = threadIdx.x >> 6;

    int bid = blockIdx.x;
    if (bid < nbH) {
        // ---------------- heavy path: A2, one row per wave -----------------
        constexpr int W = 64 / L;            // edge ways (16 for C=32, 8 for C=64)
        const int fl  = lane % L;
        const int way = lane / L;
        const uint flo = (uint)fl * 16u;

        auto gat = [&](uint c) -> uint4 {
            return *(const uint4*)((const char*)xin + (c * (uint)(2 * C) + flo));
        };
        float acc[8];
#pragma unroll
        for (int j = 0; j < 8; ++j) acc[j] = 0.f;
        auto fmadd = [&](const uint4& u, float v) {      // f16 feat x f32 val
            fma_lo(acc[0], u.x, v); fma_hi(acc[1], u.x, v);
            fma_lo(acc[2], u.y, v); fma_hi(acc[3], u.y, v);
            fma_lo(acc[4], u.z, v); fma_hi(acc[5], u.z, v);
            fma_lo(acc[6], u.w, v); fma_hi(acc[7], u.w, v);
        };
        auto fmadd_pk = [&](const uint4& u, uint pk) {   // f16 feat x f16 val
            fma_lo16(acc[0], u.x, pk); fma_hi16(acc[1], u.x, pk);
            fma_lo16(acc[2], u.y, pk); fma_hi16(acc[3], u.y, pk);
            fma_lo16(acc[4], u.z, pk); fma_hi16(acc[5], u.z, pk);
            fma_lo16(acc[6], u.w, pk); fma_hi16(acc[7], u.w, pk);
        };

        const int row = bid * 4 + wave;
        if (row >= n) return;
        const int s = ip2[row];
        const int e = ip2[row + 1];

        // unaligned head (<=3 edges), packed reads straight from global
        int sv = (s + 3) & ~3; if (sv > e) sv = e;
        for (int idx = s + way; idx < sv; idx += W) {
            const uint p = pk2[idx];
            fmadd(gat(p & 0xffffu), h2f_hi(p));
        }

        // global-array tail guard: edges >= cut handled direct-global
        const int cut = E2 & ~3;
        int ee = e;
        if (ee > cut) {
            int st = (sv > cut) ? sv : cut;
            for (int idx = st + way; idx < ee; idx += W) {
                const uint p = pk2[idx];
                fmadd(gat(p & 0xffffu), h2f_hi(p));
            }
            ee = st;
        }

        const int lastA = (E2 - 4) & ~3;     // last aligned 4-edge chunk start
        uint* myp = &spk[wave][0];

        for (int base = sv; base < ee; base += 256) {
            const int cnt = (ee - base < 256) ? (ee - base) : 256;
            // async stage this chunk's packed edges (ONE glds16: 256x4B=1KB)
            int so = base + lane * 4; if (so > lastA) so = lastA;
            glds16(pk2 + so, myp);
            asm volatile("s_waitcnt vmcnt(0)" ::: "memory");
            __builtin_amdgcn_sched_barrier(0);
            // consume: 4-edge batches per way from LDS
            const int nb = cnt / (4 * W);
            for (int b = 0; b < nb; ++b) {
                const int o = (b * W + way) * 4;
                const uint4 cc = *(const uint4*)(myp + o);
                const uint4 g0 = gat(cc.x & 0xffffu), g1 = gat(cc.y & 0xffffu),
                            g2 = gat(cc.z & 0xffffu), g3 = gat(cc.w & 0xffffu);
                fmadd_pk(g0, cc.x); fmadd_pk(g1, cc.y);
                fmadd_pk(g2, cc.z); fmadd_pk(g3, cc.w);
            }
            // per-edge tail within the chunk
            for (int k = nb * 4 * W + way; k < cnt; k += W) {
                const uint p = myp[k];
                fmadd(gat(p & 0xffffu), h2f_hi(p));
            }
        }

        // cross-way reduction (ways share a full wave here)
#pragma unroll
        for (int m = L; m < 64; m <<= 1)
#pragma unroll
            for (int j = 0; j < 8; ++j) acc[j] += __shfl_xor(acc[j], m, 64);

        if (way == 0) {
            uint4 p;
            p.x = f2h2(fmaxf(acc[0], 0.f), fmaxf(acc[1], 0.f));
            p.y = f2h2(fmaxf(acc[2], 0.f), fmaxf(acc[3], 0.f));
            p.z = f2h2(fmaxf(acc[4], 0.f), fmaxf(acc[5], 0.f));
            p.w = f2h2(fmaxf(acc[6], 0.f), fmaxf(acc[7], 0.f));
            *(uint4*)(out + (size_t)row * (2 * C) + C + fl * 8) = p;
        }
    } else {
        // ---------------- light path: A1 (R2 structure, unchanged) ---------
        bid -= nbH;
        constexpr int SUBL = 64 / ROWSL;
        constexpr int WL   = SUBL / L;
        const int sub = lane / SUBL;
        const int li  = lane % SUBL;
        const int fl  = li % L;
        const int way = li / L;
        const uint flo = (uint)fl * 16u;

        auto gat = [&](uint c) -> uint4 {
            return *(const uint4*)((const char*)xin + (c * (uint)(2 * C) + flo));
        };
        float acc[8];
#pragma unroll
        for (int j = 0; j < 8; ++j) acc[j] = 0.f;
        auto fmadd = [&](const uint4& u, float v) {
            fma_lo(acc[0], u.x, v); fma_hi(acc[1], u.x, v);
            fma_lo(acc[2], u.y, v); fma_hi(acc[3], u.y, v);
            fma_lo(acc[4], u.z, v); fma_hi(acc[5], u.z, v);
            fma_lo(acc[6], u.w, v); fma_hi(acc[7], u.w, v);
        };

        const int row = (bid * 4 + wave) * ROWSL + sub;
        if (row >= n) return;
        const int s = ip1[row];
        const int e = ip1[row + 1];
        int idx0 = s + way;
        if (idx0 < e) {
            int c0 = col1[idx0]; float v0 = val1[idx0];
            int idx1 = idx0 + WL;
            int c1 = 0; float v1 = 0.f;
            if (idx1 < e) { c1 = col1[idx1]; v1 = val1[idx1]; }
            uint4 g0 = gat((uint)c0);
            while (true) {
                int idx2 = idx1 + WL;
                int c2 = 0; float v2 = 0.f;
                if (idx2 < e) { c2 = col1[idx2]; v2 = val1[idx2]; }
                uint4 g1 = gat((uint)c1);
                fmadd(g0, v0);
                if (idx1 >= e) break;
                g0 = g1; c1 = c2; v0 = v1; v1 = v2;
                idx1 = idx2;
            }
        }
#pragma unroll
        for (int m = L; m < SUBL; m <<= 1)
#pragma unroll
            for (int j = 0; j < 8; ++j) acc[j] += __shfl_xor(acc[j], m, 64);
        if (way == 0) {
            uint4 p;
            p.x = f2h2(fmaxf(acc[0], 0.f), fmaxf(acc[1], 0.f));
            p.y = f2h2(fmaxf(acc[2], 0.f), fmaxf(acc[3], 0.f));
            p.z = f2h2(fmaxf(acc[4], 0.f), fmaxf(acc[5], 0.f));
            p.w = f2h2(fmaxf(acc[6], 0.f), fmaxf(acc[7], 0.f));
            *(uint4*)(out + (size_t)row * (2 * C) + fl * 8) = p;
        }
    }
}

// ---------------------------------------------------------------------------
// K3: classify (R8 version: 8 thr/row, 2 outs/thread, float2 weights).
// ---------------------------------------------------------------------------
#define CDIM 224
#define OUT_C 16
__global__ __launch_bounds__(256) void classify_kernel(
        const ushort* __restrict__ r0,
        const ushort* __restrict__ r1,
        const ushort* __restrict__ r2,
        const float* __restrict__ w,
        float* __restrict__ out, int n) {
    __shared__ float wl[CDIM * OUT_C];
    const int tid = threadIdx.x;
    for (int i = tid; i < CDIM * OUT_C; i += blockDim.x) wl[i] = w[i];
    __syncthreads();
    const int row = blockIdx.x * 32 + tid / 8;
    const int o   = (tid % 8) * 2;           // this thread's output pair
    if (row >= n) return;
    float acc0 = 0.f, acc1 = 0.f;

    auto wp = [&](int j) -> float2 {
        return *(const float2*)&wl[j * OUT_C + o];
    };
    auto step = [&](uint pk, int j) {
        float2 wa = wp(j);
        float2 wb = wp(j + 1);
        fma_lo(acc0, pk, wa.x); fma_lo(acc1, pk, wa.y);
        fma_hi(acc0, pk, wb.x); fma_hi(acc1, pk, wb.y);
    };

    const uint4* a = (const uint4*)(r0 + (size_t)row * 32);
#pragma unroll
    for (int q = 0; q < 4; ++q) {
        uint4 u = a[q]; int j = q * 8;
        step(u.x, j+0); step(u.y, j+2); step(u.z, j+4); step(u.w, j+6);
    }
    const uint4* b = (const uint4*)(r1 + (size_t)row * 64);
#pragma unroll
    for (int q = 0; q < 8; ++q) {
        uint4 u = b[q]; int j = 32 + q * 8;
        step(u.x, j+0); step(u.y, j+2); step(u.z, j+4); step(u.w, j+6);
    }
    const uint4* c = (const uint4*)(r2 + (size_t)row * 128);
#pragma unroll
    for (int q = 0; q < 16; ++q) {
        uint4 u = c[q]; int j = 96 + q * 8;
        step(u.x, j+0); step(u.y, j+2); step(u.z, j+4); step(u.w, j+6);
    }
    *(float2*)(out + (size_t)row * OUT_C + o) = make_float2(acc0, acc1);
}

// ---------------------------------------------------------------------------
extern "C" void kernel_launch(void* const* d_in, const int* in_sizes, int n_in,
                              void* d_out, int out_size, void* d_ws, size_t ws_size,
                              hipStream_t stream) {
    const float* x   = (const float*)d_in[0];
    const float* we  = (const float*)d_in[1];
    const float* wc  = (const float*)d_in[2];
    const int*   a1r = (const int*)  d_in[3];
    const int*   a1c = (const int*)  d_in[4];
    const float* a1v = (const float*)d_in[5];
    const int*   a2r = (const int*)  d_in[6];
    const int*   a2c = (const int*)  d_in[7];
    const float* a2v = (const float*)d_in[8];
    float* out = (float*)d_out;

    const int E1 = in_sizes[3];
    const int E2 = in_sizes[6];
    const int n  = in_sizes[0] / IN_C;   // 20000

    // Workspace: r0[n*32] r1[n*64] r2[n*128] (f16), ip1, ip2, pk2[E2]
    // (n+4) int slots per indptr keep pk2 16B-aligned.
    ushort* r0 = (ushort*)d_ws;
    ushort* r1 = r0 + (size_t)n * 32;
    ushort* r2 = r1 + (size_t)n * 64;
    int*   ip1 = (int*)(r2 + (size_t)n * 128);
    int*   ip2 = ip1 + (n + 4);
    uint*  pk2 = (uint*)(ip2 + (n + 4));

    // 1) fused embed + indptr + A2 edge repack (u16 col | f16 val)
    {
        const int nbE = (n + 15) / 16;
        const int nbI = (n + 1 + 255) / 256;
        const int nbT = 512;
        prep_kernel<<<nbE + nbI + nbT, 256, 0, stream>>>(
            x, we, r0, a1r, E1, ip1, a2r, E2, ip2, a2c, a2v, pk2,
            n, nbE, nbI, nbT);
    }

    // 2) level 1: r1 = relu([A1 r0 | A2 r0]); C=32
    //    heavy: 1 row/wave (4 rows/block); light: ROWSL=2 (8 rows/block)
    {
        const int nbH = (n + 3) / 4;
        const int nbL = (n + 7) / 8;
        spmm_level<32, 2><<<nbH + nbL, 256, 0, stream>>>(
            ip1, a1c, a1v, ip2, pk2, E2, r0, r1, n, nbH);
    }
    // 3) level 2: r2 = relu([A1 r1 | A2 r1]); C=64
    //    heavy: 1 row/wave (4 rows/block); light: ROWSL=1 (4 rows/block)
    {
        const int nbH = (n + 3) / 4;
        const int nbL = (n + 3) / 4;
        spmm_level<64, 1><<<nbH + nbL, 256, 0, stream>>>(
            ip1, a1c, a1v, ip2, pk2, E2, r1, r2, n, nbH);
    }

    // 4) fused concat + classify (32 rows/block, 2 outs/thread, b64 weights)
    classify_kernel<<<(n + 31) / 32, 256, 0, stream>>>(r0, r1, r2, wc, out, n);
}